// Round 4
// baseline (188539.246 us; speedup 1.0000x reference)
//
#include <hip/hip_runtime.h>
#include <hip/hip_bf16.h>
#include <stdint.h>
#include <stddef.h>

#define T_STEPS 262144
#define CHUNK   64
#define NCHUNK  (T_STEPS / CHUNK)

typedef float v2f __attribute__((ext_vector_type(2)));
typedef float v4f __attribute__((ext_vector_type(4)));

// packed dual-FMA: acc.lo += a.lo*b.lo ; acc.hi += a.hi*b.hi
#define PKFMA(acc, a, b) \
    asm("v_pk_fma_f32 %0, %1, %2, %0" : "+v"(acc) : "v"(a), "v"(b))

__device__ __forceinline__ v2f xload(const float* __restrict__ x, int g) {
    v2f v;
    v.x = (g     >= 0 && g     < T_STEPS * 8) ? x[g]     : 0.0f;
    v.y = (g + 1 >= 0 && g + 1 < T_STEPS * 8) ? x[g + 1] : 0.0f;
    return v;
}

// ---------------------------------------------------------------------------
// Sequential GRU scan. ONE workgroup, 256 threads = 4 waves (1 per SIMD).
// amdgpu_waves_per_eu(1,1): register budget = 512 VGPR/wave so the ~220-reg
// weight-resident working set does NOT spill (round-3 counters showed the
// allocator capped at 128 VGPR for a 4-waves/EU target and spilled weights).
// Lane (w,l): col = w*32 + (l&31) in [0,128); half = l>>5 selects rows
// [64*half, 64*half+64). Pair partner = lane^32 (same wave, shfl combine).
// Per step: 102 pk_fma + 4 shuffle-adds + 3 exp, ONE barrier.
// ---------------------------------------------------------------------------
__global__ __launch_bounds__(256)
__attribute__((amdgpu_waves_per_eu(1, 1)))
void gru_scan(
    const float* __restrict__ xg,     // even_x, [T*8]
    const float* __restrict__ gk,     // gru_kernel [8][384]
    const float* __restrict__ gr,     // gru_rec_kernel [128][384]
    const float* __restrict__ gb,     // gru_bias [2][384]
    __hip_bfloat16* __restrict__ hsT) // out: h states, transposed [128][T]
{
    const int tid  = threadIdx.x;
    const int w    = tid >> 6;
    const int l    = tid & 63;
    const int col  = (w << 5) | (l & 31);   // 0..127
    const int half = l >> 5;                // 0 or 1
    const int r0   = half << 6;             // row base: 0 or 64

    __shared__ float hbuf[2][132];          // double-buffered h (pad to 132)
    __shared__ float xsh[2][CHUNK * 8];     // double-buffered x chunks

    // ---- recurrent weights: 3 gates x 32 row-pairs (this half's 64 rows) ----
    v2f wz[32], wrv[32], wn[32];
#pragma unroll
    for (int p = 0; p < 32; ++p) {
        const int r = r0 + 2 * p;
        wz[p].x  = gr[r * 384 + col];        wz[p].y  = gr[(r + 1) * 384 + col];
        wrv[p].x = gr[r * 384 + 128 + col];  wrv[p].y = gr[(r + 1) * 384 + 128 + col];
        wn[p].x  = gr[r * 384 + 256 + col];  wn[p].y  = gr[(r + 1) * 384 + 256 + col];
    }
    // ---- input-kernel weights: this half covers x rows [4*half, 4*half+4) ----
    v2f kz[2], kr[2], kn[2];
#pragma unroll
    for (int p = 0; p < 2; ++p) {
        const int r = 4 * half + 2 * p;
        kz[p].x = gk[r * 384 + col];         kz[p].y = gk[(r + 1) * 384 + col];
        kr[p].x = gk[r * 384 + 128 + col];   kr[p].y = gk[(r + 1) * 384 + 128 + col];
        kn[p].x = gk[r * 384 + 256 + col];   kn[p].y = gk[(r + 1) * 384 + 256 + col];
    }
    const float bz  = gb[col]       + gb[384 + col];   // z: b_i + b_r
    const float brc = gb[128 + col] + gb[512 + col];   // r: b_i + b_r
    const float bin = gb[256 + col];                   // n: input bias
    const float brn = gb[640 + col];                   // n: recurrent bias

    if (tid < 128) hbuf[0][tid] = 0.0f;                // h0 = 0
    // prefetch x chunk 0 (shift-by-one folded in: slot s holds even_x[t-1])
    v2f px = xload(xg, -8 + tid * 2);
    __syncthreads();

    for (int c = 0; c < NCHUNK; ++c) {
        const int cb = c & 1;
        // stage prefetched x (compiler inserts the vmcnt wait for px)
        xsh[cb][2 * tid]     = px.x;
        xsh[cb][2 * tid + 1] = px.y;
        if (c + 1 < NCHUNK) px = xload(xg, (c + 1) * (CHUNK * 8) - 8 + tid * 2);
        asm volatile("s_waitcnt lgkmcnt(0)" ::: "memory");
        __builtin_amdgcn_s_barrier();

#pragma unroll 1
        for (int s = 0; s < CHUNK; ++s) {
            const int t  = (c << 6) + s;
            const int rb = s & 1;              // read buffer (64 is even)
            const v4f* hq = ((const v4f*)&hbuf[rb][0]) + (half << 4);

            v2f az0 = {0.f, 0.f}, az1 = {0.f, 0.f};
            v2f ar0 = {0.f, 0.f}, ar1 = {0.f, 0.f};
            v2f an0 = {0.f, 0.f}, an1 = {0.f, 0.f};
#pragma unroll
            for (int m = 0; m < 16; ++m) {
                const v4f h4 = hq[m];          // broadcast LDS read, 4 h values
                v2f ha; ha.x = h4.x; ha.y = h4.y;
                v2f hb; hb.x = h4.z; hb.y = h4.w;
                PKFMA(az0, ha, wz[2 * m]);   PKFMA(az1, hb, wz[2 * m + 1]);
                PKFMA(ar0, ha, wrv[2 * m]);  PKFMA(ar1, hb, wrv[2 * m + 1]);
                PKFMA(an0, ha, wn[2 * m]);   PKFMA(an1, hb, wn[2 * m + 1]);
            }
            // input projection: this half's 4 x-features
            const v4f xq = ((const v4f*)&xsh[cb][s * 8])[half];
            v2f xa;  xa.x  = xq.x; xa.y  = xq.y;
            v2f xb2; xb2.x = xq.z; xb2.y = xq.w;
            PKFMA(az0, xa, kz[0]); PKFMA(az1, xb2, kz[1]);
            PKFMA(ar0, xa, kr[0]); PKFMA(ar1, xb2, kr[1]);
            v2f gxn2 = {0.f, 0.f};
            PKFMA(gxn2, xa, kn[0]); PKFMA(gxn2, xb2, kn[1]);

            const float hold = hbuf[rb][col];

            float pz  = (az0.x + az0.y) + (az1.x + az1.y);
            float pr  = (ar0.x + ar0.y) + (ar1.x + ar1.y);
            float pn  = (an0.x + an0.y) + (an1.x + an1.y);
            float pxn = gxn2.x + gxn2.y;
            // combine pair halves (partner holds the other 64 rows / 4 feats)
            pz  += __shfl_xor(pz, 32);
            pr  += __shfl_xor(pr, 32);
            pn  += __shfl_xor(pn, 32);
            pxn += __shfl_xor(pxn, 32);

            const float zarg = pz + bz;
            const float rarg = pr + brc;
            const float hn   = pn + brn;         // recurrent n (gets gated by r)
            const float xh   = pxn + bin;        // input n
            const float z  = 1.0f / (1.0f + __expf(-zarg));
            const float rg = 1.0f / (1.0f + __expf(-rarg));
            const float hh = 1.0f - 2.0f / (1.0f + __expf(2.0f * fmaf(rg, hn, xh)));
            const float hnew = fmaf(z, hold - hh, hh);   // z*h + (1-z)*hh

            if (half == 0) {
                hbuf[rb ^ 1][col] = hnew;                 // next step's h
            } else {
                // fire-and-forget bf16 store, transposed; L2 merges over t
                hsT[(size_t)col * T_STEPS + t] = __float2bfloat16(hnew);
            }
            // LDS-only wait: do NOT drain vmcnt (stores stay in flight)
            asm volatile("s_waitcnt lgkmcnt(0)" ::: "memory");
            __builtin_amdgcn_s_barrier();
        }
    }
}

// ---------------------------------------------------------------------------
// Dense tail: y[t][:] = hs[t][:] @ dk + db. Thread per t, W staged in LDS,
// float4 broadcast reads, coalesced bf16 reads from transposed hsT.
// ---------------------------------------------------------------------------
__global__ __launch_bounds__(256) void dense_out(
    const __hip_bfloat16* __restrict__ hsT,  // [128][T]
    const float* __restrict__ dk,            // [128][96]
    const float* __restrict__ db,            // [96]
    float* __restrict__ out)                 // [T][96]
{
    __shared__ float wl[128 * 96];
    for (int k = threadIdx.x; k < 128 * 96; k += 256) wl[k] = dk[k];
    __syncthreads();

    const int t = blockIdx.x * 256 + threadIdx.x;
    v4f acc[24];
#pragma unroll
    for (int o = 0; o < 24; ++o) acc[o] = ((const v4f*)db)[o];

#pragma unroll 4
    for (int i = 0; i < 128; ++i) {
        const float h = __bfloat162float(hsT[(size_t)i * T_STEPS + t]);
        const v4f* wp = (const v4f*)&wl[i * 96];
#pragma unroll
        for (int o = 0; o < 24; ++o) {
            const v4f wv = wp[o];
            acc[o].x = fmaf(h, wv.x, acc[o].x);
            acc[o].y = fmaf(h, wv.y, acc[o].y);
            acc[o].z = fmaf(h, wv.z, acc[o].z);
            acc[o].w = fmaf(h, wv.w, acc[o].w);
        }
    }
    v4f* op = (v4f*)(out + (size_t)t * 96);
#pragma unroll
    for (int o = 0; o < 24; ++o) op[o] = acc[o];
}

// ---------------------------------------------------------------------------
extern "C" void kernel_launch(void* const* d_in, const int* in_sizes, int n_in,
                              void* d_out, int out_size, void* d_ws, size_t ws_size,
                              hipStream_t stream) {
    const float* even_x = (const float*)d_in[0];
    const float* gk     = (const float*)d_in[1];
    const float* gr     = (const float*)d_in[2];
    const float* gb     = (const float*)d_in[3];
    const float* dk     = (const float*)d_in[4];
    const float* db     = (const float*)d_in[5];
    float* out          = (float*)d_out;

    // hsT needs 128*T*2 = 64 MiB. Guard against an undersized workspace:
    // fall back to d_out (valid 96 MiB) — output then fails absmax (tripwire)
    // instead of faulting the GPU with OOB writes.
    const size_t need = (size_t)128 * T_STEPS * sizeof(__hip_bfloat16);
    __hip_bfloat16* hsT = (ws_size >= need) ? (__hip_bfloat16*)d_ws
                                            : (__hip_bfloat16*)d_out;

    gru_scan<<<1, 256, 0, stream>>>(even_x, gk, gr, gb, hsT);
    dense_out<<<T_STEPS / 256, 256, 0, stream>>>(hsT, dk, db, out);
}

// Round 5
// 185105.554 us; speedup vs baseline: 1.0185x; 1.0185x over previous
//
#include <hip/hip_runtime.h>
#include <hip/hip_bf16.h>
#include <stdint.h>
#include <stddef.h>

#define T_STEPS 262144
#define CHUNK   64
#define NCHUNK  (T_STEPS / CHUNK)

typedef float v2f __attribute__((ext_vector_type(2)));
typedef float v4f __attribute__((ext_vector_type(4)));

// packed dual-FMA: acc.lo += a.lo*b.lo ; acc.hi += a.hi*b.hi
#define PKFMA(acc, a, b) \
    asm("v_pk_fma_f32 %0, %1, %2, %0" : "+v"(acc) : "v"(a), "v"(b))

__device__ __forceinline__ v2f xload(const float* __restrict__ x, int g) {
    v2f v;
    v.x = (g     >= 0 && g     < T_STEPS * 8) ? x[g]     : 0.0f;
    v.y = (g + 1 >= 0 && g + 1 < T_STEPS * 8) ? x[g + 1] : 0.0f;
    return v;
}

#define FOR32(M) M(0) M(1) M(2) M(3) M(4) M(5) M(6) M(7) \
                 M(8) M(9) M(10) M(11) M(12) M(13) M(14) M(15) \
                 M(16) M(17) M(18) M(19) M(20) M(21) M(22) M(23) \
                 M(24) M(25) M(26) M(27) M(28) M(29) M(30) M(31)

// ---------------------------------------------------------------------------
// Sequential GRU scan. ONE workgroup, 256 threads = 4 waves (1 per SIMD).
// Round-5 change: weight storage is 96 INDIVIDUALLY NAMED v2f variables
// (macro-expanded) instead of v2f arrays. Rounds 3/4 showed ~130 VGPRs and
// ~1700 cyc/step regardless of occupancy attributes: the arrays were demoted
// to scratch (SROA can't split runtime-indexed ext_vector arrays; guide rule
// #20), so every step re-streamed ~780 B/lane of weights from scratch.
// Named scalars cannot be demoted. amdgpu_num_vgpr(256) additionally pins the
// full architected VGPR file (demand ~235).
// ---------------------------------------------------------------------------
__global__ __launch_bounds__(256)
__attribute__((amdgpu_num_vgpr(256)))
void gru_scan(
    const float* __restrict__ xg,     // even_x, [T*8]
    const float* __restrict__ gk,     // gru_kernel [8][384]
    const float* __restrict__ gr,     // gru_rec_kernel [128][384]
    const float* __restrict__ gb,     // gru_bias [2][384]
    __hip_bfloat16* __restrict__ hsT) // out: h states, transposed [128][T]
{
    const int tid  = threadIdx.x;
    const int w    = tid >> 6;
    const int l    = tid & 63;
    const int col  = (w << 5) | (l & 31);   // 0..127
    const int half = l >> 5;                // 0 or 1
    const int r0   = half << 6;             // row base: 0 or 64

    __shared__ float hbuf[2][132];          // double-buffered h (pad to 132)
    __shared__ float xsh[2][CHUNK * 8];     // double-buffered x chunks

    // ---- recurrent weights: 96 NAMED v2f (3 gates x 32 row-pairs) ----
#define DECLW(p) v2f wz##p, wr##p, wn##p;
    FOR32(DECLW)
#undef DECLW
#define LOADW(p) { const int r = r0 + 2 * (p); \
    wz##p.x = gr[r * 384 + col];        wz##p.y = gr[(r + 1) * 384 + col]; \
    wr##p.x = gr[r * 384 + 128 + col];  wr##p.y = gr[(r + 1) * 384 + 128 + col]; \
    wn##p.x = gr[r * 384 + 256 + col];  wn##p.y = gr[(r + 1) * 384 + 256 + col]; }
    FOR32(LOADW)
#undef LOADW

    // ---- input-kernel weights (named; this half covers x rows 4*half..+3) ----
    v2f kz0, kz1, kr0, kr1, kn0, kn1;
    {
        const int r = 4 * half;
        kz0.x = gk[r * 384 + col];           kz0.y = gk[(r + 1) * 384 + col];
        kz1.x = gk[(r + 2) * 384 + col];     kz1.y = gk[(r + 3) * 384 + col];
        kr0.x = gk[r * 384 + 128 + col];     kr0.y = gk[(r + 1) * 384 + 128 + col];
        kr1.x = gk[(r + 2) * 384 + 128 + col]; kr1.y = gk[(r + 3) * 384 + 128 + col];
        kn0.x = gk[r * 384 + 256 + col];     kn0.y = gk[(r + 1) * 384 + 256 + col];
        kn1.x = gk[(r + 2) * 384 + 256 + col]; kn1.y = gk[(r + 3) * 384 + 256 + col];
    }
    const float bz  = gb[col]       + gb[384 + col];   // z: b_i + b_r
    const float brc = gb[128 + col] + gb[512 + col];   // r: b_i + b_r
    const float bin = gb[256 + col];                   // n: input bias
    const float brn = gb[640 + col];                   // n: recurrent bias

    if (tid < 128) hbuf[0][tid] = 0.0f;                // h0 = 0
    float hprev = 0.0f;                                // h[col] carried in-reg
    // prefetch x chunk 0 (shift-by-one folded in: slot s holds even_x[t-1])
    v2f px = xload(xg, -8 + tid * 2);
    __syncthreads();

    for (int c = 0; c < NCHUNK; ++c) {
        const int cb = c & 1;
        xsh[cb][2 * tid]     = px.x;
        xsh[cb][2 * tid + 1] = px.y;
        if (c + 1 < NCHUNK) px = xload(xg, (c + 1) * (CHUNK * 8) - 8 + tid * 2);
        asm volatile("s_waitcnt lgkmcnt(0)" ::: "memory");
        __builtin_amdgcn_s_barrier();

#pragma unroll 1
        for (int s = 0; s < CHUNK; ++s) {
            const int t  = (c << 6) + s;
            const int rb = s & 1;              // read buffer (64 is even)
            const v4f* hq = ((const v4f*)&hbuf[rb][0]) + (half << 4);

            v2f az0 = {0.f, 0.f}, az1 = {0.f, 0.f};
            v2f ar0 = {0.f, 0.f}, ar1 = {0.f, 0.f};
            v2f an0 = {0.f, 0.f}, an1 = {0.f, 0.f};

#define QROW(m, pa, pb) { const v4f h4 = hq[m]; \
    const v2f ha = __builtin_shufflevector(h4, h4, 0, 1); \
    const v2f hb = __builtin_shufflevector(h4, h4, 2, 3); \
    PKFMA(az0, ha, wz##pa); PKFMA(az1, hb, wz##pb); \
    PKFMA(ar0, ha, wr##pa); PKFMA(ar1, hb, wr##pb); \
    PKFMA(an0, ha, wn##pa); PKFMA(an1, hb, wn##pb); }
            QROW(0, 0, 1)   QROW(1, 2, 3)   QROW(2, 4, 5)   QROW(3, 6, 7)
            QROW(4, 8, 9)   QROW(5, 10, 11) QROW(6, 12, 13) QROW(7, 14, 15)
            QROW(8, 16, 17) QROW(9, 18, 19) QROW(10, 20, 21) QROW(11, 22, 23)
            QROW(12, 24, 25) QROW(13, 26, 27) QROW(14, 28, 29) QROW(15, 30, 31)
#undef QROW

            // input projection: this half's 4 x-features
            const v4f xq = ((const v4f*)&xsh[cb][s * 8])[half];
            const v2f xa  = __builtin_shufflevector(xq, xq, 0, 1);
            const v2f xb2 = __builtin_shufflevector(xq, xq, 2, 3);
            PKFMA(az0, xa, kz0); PKFMA(az1, xb2, kz1);
            PKFMA(ar0, xa, kr0); PKFMA(ar1, xb2, kr1);
            v2f gxn2 = {0.f, 0.f};
            PKFMA(gxn2, xa, kn0); PKFMA(gxn2, xb2, kn1);

            float pz  = (az0.x + az0.y) + (az1.x + az1.y);
            float pr  = (ar0.x + ar0.y) + (ar1.x + ar1.y);
            float pn  = (an0.x + an0.y) + (an1.x + an1.y);
            float pxn = gxn2.x + gxn2.y;
            // combine pair halves (partner holds the other 64 rows / 4 feats)
            pz  += __shfl_xor(pz, 32);
            pr  += __shfl_xor(pr, 32);
            pn  += __shfl_xor(pn, 32);
            pxn += __shfl_xor(pxn, 32);

            const float zarg = pz + bz;
            const float rarg = pr + brc;
            const float hn   = pn + brn;         // recurrent n (gated by r)
            const float xh   = pxn + bin;        // input n
            const float z  = 1.0f / (1.0f + __expf(-zarg));
            const float rg = 1.0f / (1.0f + __expf(-rarg));
            const float hh = 1.0f - 2.0f / (1.0f + __expf(2.0f * fmaf(rg, hn, xh)));
            const float hnew = fmaf(z, hprev - hh, hh);  // z*h + (1-z)*hh
            hprev = hnew;                                // carry in-register

            if (half == 0) {
                hbuf[rb ^ 1][col] = hnew;                 // next step's h
            } else {
                // fire-and-forget bf16 store, transposed; L2 merges over t
                hsT[(size_t)col * T_STEPS + t] = __float2bfloat16(hnew);
            }
            // LDS-only wait: do NOT drain vmcnt (stores stay in flight)
            asm volatile("s_waitcnt lgkmcnt(0)" ::: "memory");
            __builtin_amdgcn_s_barrier();
        }
    }
}

// ---------------------------------------------------------------------------
// Dense tail: y[t][:] = hs[t][:] @ dk + db. Thread per t, W staged in LDS,
// float4 broadcast reads, coalesced bf16 reads from transposed hsT.
// ---------------------------------------------------------------------------
__global__ __launch_bounds__(256) void dense_out(
    const __hip_bfloat16* __restrict__ hsT,  // [128][T]
    const float* __restrict__ dk,            // [128][96]
    const float* __restrict__ db,            // [96]
    float* __restrict__ out)                 // [T][96]
{
    __shared__ float wl[128 * 96];
    for (int k = threadIdx.x; k < 128 * 96; k += 256) wl[k] = dk[k];
    __syncthreads();

    const int t = blockIdx.x * 256 + threadIdx.x;
    v4f acc[24];
#pragma unroll
    for (int o = 0; o < 24; ++o) acc[o] = ((const v4f*)db)[o];

#pragma unroll 4
    for (int i = 0; i < 128; ++i) {
        const float h = __bfloat162float(hsT[(size_t)i * T_STEPS + t]);
        const v4f* wp = (const v4f*)&wl[i * 96];
#pragma unroll
        for (int o = 0; o < 24; ++o) {
            const v4f wv = wp[o];
            acc[o].x = fmaf(h, wv.x, acc[o].x);
            acc[o].y = fmaf(h, wv.y, acc[o].y);
            acc[o].z = fmaf(h, wv.z, acc[o].z);
            acc[o].w = fmaf(h, wv.w, acc[o].w);
        }
    }
    v4f* op = (v4f*)(out + (size_t)t * 96);
#pragma unroll
    for (int o = 0; o < 24; ++o) op[o] = acc[o];
}

// ---------------------------------------------------------------------------
extern "C" void kernel_launch(void* const* d_in, const int* in_sizes, int n_in,
                              void* d_out, int out_size, void* d_ws, size_t ws_size,
                              hipStream_t stream) {
    const float* even_x = (const float*)d_in[0];
    const float* gk     = (const float*)d_in[1];
    const float* gr     = (const float*)d_in[2];
    const float* gb     = (const float*)d_in[3];
    const float* dk     = (const float*)d_in[4];
    const float* db     = (const float*)d_in[5];
    float* out          = (float*)d_out;

    // hsT needs 128*T*2 = 64 MiB. Guard against an undersized workspace:
    // fall back to d_out (valid 96 MiB) — output then fails absmax (tripwire)
    // instead of faulting the GPU with OOB writes.
    const size_t need = (size_t)128 * T_STEPS * sizeof(__hip_bfloat16);
    __hip_bfloat16* hsT = (ws_size >= need) ? (__hip_bfloat16*)d_ws
                                            : (__hip_bfloat16*)d_out;

    gru_scan<<<1, 256, 0, stream>>>(even_x, gk, gr, gb, hsT);
    dense_out<<<T_STEPS / 256, 256, 0, stream>>>(hsT, dk, db, out);
}

// Round 7
// 165757.141 us; speedup vs baseline: 1.1374x; 1.1167x over previous
//
#include <hip/hip_runtime.h>
#include <hip/hip_bf16.h>
#include <stdint.h>
#include <stddef.h>

#define T_STEPS 262144
#define CHUNK   64
#define NCHUNK  (T_STEPS / CHUNK)

typedef float v2f __attribute__((ext_vector_type(2)));
typedef float v4f __attribute__((ext_vector_type(4)));

// packed dual-FMA: acc.lo += a.lo*b.lo ; acc.hi += a.hi*b.hi
#define PKFMA(acc, a, b) \
    asm("v_pk_fma_f32 %0, %1, %2, %0" : "+v"(acc) : "v"(a), "v"(b))

// quad-lane XOR swaps via DPP quad_perm (VALU-speed, no LDS):
// xor1: perm [1,0,3,2] = 0xB1 ; xor2: perm [2,3,0,1] = 0x4E
__device__ __forceinline__ float dpp_xor1(float x) {
    int y = __builtin_amdgcn_mov_dpp(__builtin_bit_cast(int, x), 0xB1, 0xF, 0xF, true);
    return __builtin_bit_cast(float, y);
}
__device__ __forceinline__ float dpp_xor2(float x) {
    int y = __builtin_amdgcn_mov_dpp(__builtin_bit_cast(int, x), 0x4E, 0xF, 0xF, true);
    return __builtin_bit_cast(float, y);
}

#define FOR16(M) M(0) M(1) M(2) M(3) M(4) M(5) M(6) M(7) \
                 M(8) M(9) M(10) M(11) M(12) M(13) M(14) M(15)

// ---------------------------------------------------------------------------
// Sequential GRU scan: 512 threads = 8 waves (2/SIMD).
// Lane (col = tid>>2, q = tid&3) owns rows [32q, 32q+32) of column col:
// 48 named v2f weights = 96 VGPRs (~135 total, fits the 128-VGPR regime the
// allocator enforces; rounds 3-5 showed AGPR-shuttle VALU traffic otherwise).
// Quad partial-sums reduced with two DPP quad_perm hops (no LDS, no barrier).
// h replicated x4 in LDS; ROUND-7 FIX: read replica at row offset rq
// (round 6 read rows [0,32) for every q -> absmax 1.01).
// ONE barrier per step.
// ---------------------------------------------------------------------------
__global__ __launch_bounds__(512) void gru_scan(
    const float* __restrict__ xg,     // even_x, [T*8]
    const float* __restrict__ gk,     // gru_kernel [8][384]
    const float* __restrict__ gr,     // gru_rec_kernel [128][384]
    const float* __restrict__ gb,     // gru_bias [2][384]
    __hip_bfloat16* __restrict__ hsT) // out: h states, transposed [128][T]
{
    const int tid = threadIdx.x;
    const int col = tid >> 2;          // 0..127
    const int q   = tid & 3;           // row quarter
    const int rq  = q << 5;            // 32*q

    __shared__ float hbuf[2][4][132];  // h, x4 replicated (528B regions)
    __shared__ float xsh[2][512];      // double-buffered x chunks (64 steps)

    // ---- recurrent weights: 48 NAMED v2f (3 gates x 16 row-pairs) ----
#define DECLW(p) v2f wz##p, wr##p, wn##p;
    FOR16(DECLW)
#undef DECLW
#define LOADW(p) { const int r = rq + 2 * (p); \
    wz##p.x = gr[r * 384 + col];        wz##p.y = gr[(r + 1) * 384 + col]; \
    wr##p.x = gr[r * 384 + 128 + col];  wr##p.y = gr[(r + 1) * 384 + 128 + col]; \
    wn##p.x = gr[r * 384 + 256 + col];  wn##p.y = gr[(r + 1) * 384 + 256 + col]; }
    FOR16(LOADW)
#undef LOADW

    // ---- input-kernel weights: this lane covers x features {2q, 2q+1} ----
    v2f kz, kr, kn;
    {
        const int f = q << 1;
        kz.x = gk[f * 384 + col];        kz.y = gk[(f + 1) * 384 + col];
        kr.x = gk[f * 384 + 128 + col];  kr.y = gk[(f + 1) * 384 + 128 + col];
        kn.x = gk[f * 384 + 256 + col];  kn.y = gk[(f + 1) * 384 + 256 + col];
    }
    const float bz  = gb[col]       + gb[384 + col];   // z: b_i + b_r
    const float brc = gb[128 + col] + gb[512 + col];   // r: b_i + b_r
    const float bin = gb[256 + col];                   // n: input bias
    const float brn = gb[640 + col];                   // n: recurrent bias

    if (tid < 128) {                                   // h0 = 0, all replicas
        hbuf[0][0][tid] = 0.0f; hbuf[0][1][tid] = 0.0f;
        hbuf[0][2][tid] = 0.0f; hbuf[0][3][tid] = 0.0f;
    }
    float hprev = 0.0f;                                // h[col], all lanes
    // prefetch x chunk 0 (shift-by-one folded in: slot s holds even_x[t-1])
    float px = (tid >= 8) ? xg[tid - 8] : 0.0f;
    __syncthreads();

    for (int c = 0; c < NCHUNK; ++c) {
        const int cb = c & 1;
        xsh[cb][tid] = px;
        if (c + 1 < NCHUNK) px = xg[(c + 1) * 512 - 8 + tid];
        asm volatile("s_waitcnt lgkmcnt(0)" ::: "memory");
        __builtin_amdgcn_s_barrier();

#pragma unroll 1
        for (int s = 0; s < CHUNK; ++s) {
            const int t  = (c << 6) + s;
            const int rb = s & 1;              // read buffer (64 is even)
            // THIS lane's 32 h rows: replica q, rows [rq, rq+32)
            const v4f* hq = (const v4f*)&hbuf[rb][q][rq];

            v2f az0 = {0.f, 0.f}, az1 = {0.f, 0.f};
            v2f ar0 = {0.f, 0.f}, ar1 = {0.f, 0.f};
            v2f an0 = {0.f, 0.f}, an1 = {0.f, 0.f};

#define QROW(m, pa, pb) { const v4f h4 = hq[m]; \
    const v2f ha = __builtin_shufflevector(h4, h4, 0, 1); \
    const v2f hb = __builtin_shufflevector(h4, h4, 2, 3); \
    PKFMA(az0, ha, wz##pa); PKFMA(az1, hb, wz##pb); \
    PKFMA(ar0, ha, wr##pa); PKFMA(ar1, hb, wr##pb); \
    PKFMA(an0, ha, wn##pa); PKFMA(an1, hb, wn##pb); }
            QROW(0, 0, 1)  QROW(1, 2, 3)   QROW(2, 4, 5)   QROW(3, 6, 7)
            QROW(4, 8, 9)  QROW(5, 10, 11) QROW(6, 12, 13) QROW(7, 14, 15)
#undef QROW

            // input projection: this lane's 2 x-features
            const v2f xv = *(const v2f*)&xsh[cb][(s << 3) + (q << 1)];
            PKFMA(az0, xv, kz);
            PKFMA(ar0, xv, kr);
            v2f gx = {0.f, 0.f};
            PKFMA(gx, xv, kn);

            const v2f azs = az0 + az1;         // v_pk_add_f32
            const v2f ars = ar0 + ar1;
            const v2f ans = an0 + an1;
            float pz  = azs.x + azs.y;
            float pr  = ars.x + ars.y;
            float pn  = ans.x + ans.y;
            float pxn = gx.x + gx.y;
            // quad reduction over q (rows 0..127 + all 8 features)
            pz  += dpp_xor1(pz);  pz  += dpp_xor2(pz);
            pr  += dpp_xor1(pr);  pr  += dpp_xor2(pr);
            pn  += dpp_xor1(pn);  pn  += dpp_xor2(pn);
            pxn += dpp_xor1(pxn); pxn += dpp_xor2(pxn);

            const float zarg = pz + bz;
            const float rarg = pr + brc;
            const float hn   = pn + brn;         // recurrent n (gated by r)
            const float xh   = pxn + bin;        // input n
            const float z  = 1.0f / (1.0f + __expf(-zarg));
            const float rg = 1.0f / (1.0f + __expf(-rarg));
            const float hh = 1.0f - 2.0f / (1.0f + __expf(2.0f * fmaf(rg, hn, xh)));
            const float hnew = fmaf(z, hprev - hh, hh);  // z*h + (1-z)*hh
            hprev = hnew;

            hbuf[rb ^ 1][q][col] = hnew;         // every lane: own replica
            if (q == 1) {
                // fire-and-forget bf16 store, transposed; L2 merges over t
                hsT[(size_t)col * T_STEPS + t] = __float2bfloat16(hnew);
            }
            // LDS-only wait: do NOT drain vmcnt (stores stay in flight)
            asm volatile("s_waitcnt lgkmcnt(0)" ::: "memory");
            __builtin_amdgcn_s_barrier();
        }
    }
}

// ---------------------------------------------------------------------------
// Dense tail: y[t][:] = hs[t][:] @ dk + db. Thread per t, W staged in LDS,
// float4 broadcast reads, coalesced bf16 reads from transposed hsT.
// ---------------------------------------------------------------------------
__global__ __launch_bounds__(256) void dense_out(
    const __hip_bfloat16* __restrict__ hsT,  // [128][T]
    const float* __restrict__ dk,            // [128][96]
    const float* __restrict__ db,            // [96]
    float* __restrict__ out)                 // [T][96]
{
    __shared__ float wl[128 * 96];
    for (int k = threadIdx.x; k < 128 * 96; k += 256) wl[k] = dk[k];
    __syncthreads();

    const int t = blockIdx.x * 256 + threadIdx.x;
    v4f acc[24];
#pragma unroll
    for (int o = 0; o < 24; ++o) acc[o] = ((const v4f*)db)[o];

#pragma unroll 4
    for (int i = 0; i < 128; ++i) {
        const float h = __bfloat162float(hsT[(size_t)i * T_STEPS + t]);
        const v4f* wp = (const v4f*)&wl[i * 96];
#pragma unroll
        for (int o = 0; o < 24; ++o) {
            const v4f wv = wp[o];
            acc[o].x = fmaf(h, wv.x, acc[o].x);
            acc[o].y = fmaf(h, wv.y, acc[o].y);
            acc[o].z = fmaf(h, wv.z, acc[o].z);
            acc[o].w = fmaf(h, wv.w, acc[o].w);
        }
    }
    v4f* op = (v4f*)(out + (size_t)t * 96);
#pragma unroll
    for (int o = 0; o < 24; ++o) op[o] = acc[o];
}

// ---------------------------------------------------------------------------
extern "C" void kernel_launch(void* const* d_in, const int* in_sizes, int n_in,
                              void* d_out, int out_size, void* d_ws, size_t ws_size,
                              hipStream_t stream) {
    const float* even_x = (const float*)d_in[0];
    const float* gk     = (const float*)d_in[1];
    const float* gr     = (const float*)d_in[2];
    const float* gb     = (const float*)d_in[3];
    const float* dk     = (const float*)d_in[4];
    const float* db     = (const float*)d_in[5];
    float* out          = (float*)d_out;

    // hsT needs 128*T*2 = 64 MiB. Guard against an undersized workspace:
    // fall back to d_out (valid 96 MiB) — output then fails absmax (tripwire)
    // instead of faulting the GPU with OOB writes.
    const size_t need = (size_t)128 * T_STEPS * sizeof(__hip_bfloat16);
    __hip_bfloat16* hsT = (ws_size >= need) ? (__hip_bfloat16*)d_ws
                                            : (__hip_bfloat16*)d_out;

    gru_scan<<<1, 512, 0, stream>>>(even_x, gk, gr, gb, hsT);
    dense_out<<<T_STEPS / 256, 256, 0, stream>>>(hsT, dk, db, out);
}

// Round 8
// 140094.556 us; speedup vs baseline: 1.3458x; 1.1832x over previous
//
#include <hip/hip_runtime.h>
#include <hip/hip_bf16.h>
#include <stdint.h>
#include <stddef.h>

#define T_STEPS 262144
#define CHUNK   64
#define NCHUNK  (T_STEPS / CHUNK)
#define LOG2E   1.442695041f

typedef float v2f __attribute__((ext_vector_type(2)));
typedef float v4f __attribute__((ext_vector_type(4)));
typedef unsigned int v4u __attribute__((ext_vector_type(4)));

// quad-lane XOR swaps via DPP quad_perm (VALU-speed, no LDS):
// xor1: perm [1,0,3,2] = 0xB1 ; xor2: perm [2,3,0,1] = 0x4E
__device__ __forceinline__ float dpp_xor1(float x) {
    int y = __builtin_amdgcn_mov_dpp(__builtin_bit_cast(int, x), 0xB1, 0xF, 0xF, true);
    return __builtin_bit_cast(float, y);
}
__device__ __forceinline__ float dpp_xor2(float x) {
    int y = __builtin_amdgcn_mov_dpp(__builtin_bit_cast(int, x), 0x4E, 0xF, 0xF, true);
    return __builtin_bit_cast(float, y);
}

// native 1-ulp ops (avoid IEEE div slow path; no fast-math in harness)
__device__ __forceinline__ float rcpf_(float x)  { return __builtin_amdgcn_rcpf(x); }
__device__ __forceinline__ float exp2f_(float x) { return __builtin_amdgcn_exp2f(x); }

#define FOR16(M) M(0) M(1) M(2) M(3) M(4) M(5) M(6) M(7) \
                 M(8) M(9) M(10) M(11) M(12) M(13) M(14) M(15)

// ---------------------------------------------------------------------------
// Sequential GRU scan: 512 threads = 8 waves (2/SIMD).
// Lane (col = tid>>2, q = tid&3) owns rows [32q, 32q+32) of column col.
// ROUND-8 CHANGES (round 7: VGPR=72 < 96-reg weight set => AGPR overflow, and
// the old inline-asm "v" constraints forced v_accvgpr_read shuttles per use):
//  1. no inline asm -- __builtin_elementwise_fma lets the compiler keep
//     weights in AGPRs and read them DIRECTLY in v_pk_fma_f32 (unified file),
//     or allocate VGPRs as it sees fit. Single accumulator per gate (-6 regs).
//  2. sigmoids/tanh via native v_rcp_f32/v_exp_f32 (no IEEE-div sequence).
//  3. h history staged in LDS (hist[64][128] bf16), flushed once per chunk
//     as coalesced 16B stores -- zero per-step VMEM.
// Quad partial-sums reduced with two DPP quad_perm hops. ONE barrier/step.
// ---------------------------------------------------------------------------
__global__ __launch_bounds__(512, 2) void gru_scan(
    const float* __restrict__ xg,     // even_x, [T*8]
    const float* __restrict__ gk,     // gru_kernel [8][384]
    const float* __restrict__ gr,     // gru_rec_kernel [128][384]
    const float* __restrict__ gb,     // gru_bias [2][384]
    __hip_bfloat16* __restrict__ hsT) // out: h states, transposed [128][T]
{
    const int tid = threadIdx.x;
    const int col = tid >> 2;          // 0..127
    const int q   = tid & 3;           // row quarter
    const int rq  = q << 5;            // 32*q

    __shared__ float hbuf[2][4][132];          // h, x4 replicated
    __shared__ float xsh[2][512];              // double-buffered x chunks
    __shared__ __hip_bfloat16 hist[CHUNK][128]; // h history, flushed per chunk

    // ---- recurrent weights: 48 NAMED v2f (3 gates x 16 row-pairs) ----
#define DECLW(p) v2f wz##p, wr##p, wn##p;
    FOR16(DECLW)
#undef DECLW
#define LOADW(p) { const int r = rq + 2 * (p); \
    wz##p.x = gr[r * 384 + col];        wz##p.y = gr[(r + 1) * 384 + col]; \
    wr##p.x = gr[r * 384 + 128 + col];  wr##p.y = gr[(r + 1) * 384 + 128 + col]; \
    wn##p.x = gr[r * 384 + 256 + col];  wn##p.y = gr[(r + 1) * 384 + 256 + col]; }
    FOR16(LOADW)
#undef LOADW

    // ---- input-kernel weights: this lane covers x features {2q, 2q+1} ----
    v2f kz, kr, kn;
    {
        const int f = q << 1;
        kz.x = gk[f * 384 + col];        kz.y = gk[(f + 1) * 384 + col];
        kr.x = gk[f * 384 + 128 + col];  kr.y = gk[(f + 1) * 384 + 128 + col];
        kn.x = gk[f * 384 + 256 + col];  kn.y = gk[(f + 1) * 384 + 256 + col];
    }
    const float bz  = gb[col]       + gb[384 + col];   // z: b_i + b_r
    const float brc = gb[128 + col] + gb[512 + col];   // r: b_i + b_r
    const float bin = gb[256 + col];                   // n: input bias
    const float brn = gb[640 + col];                   // n: recurrent bias

    if (tid < 128) {                                   // h0 = 0, all replicas
        hbuf[0][0][tid] = 0.0f; hbuf[0][1][tid] = 0.0f;
        hbuf[0][2][tid] = 0.0f; hbuf[0][3][tid] = 0.0f;
    }
    float hprev = 0.0f;                                // h[col], all lanes
    // prefetch x chunk 0 (shift-by-one folded in: slot s holds even_x[t-1])
    float px = (tid >= 8) ? xg[tid - 8] : 0.0f;
    __syncthreads();

    for (int c = 0; c < NCHUNK; ++c) {
        const int cb = c & 1;
        xsh[cb][tid] = px;
        if (c + 1 < NCHUNK) px = xg[(c + 1) * 512 - 8 + tid];
        asm volatile("s_waitcnt lgkmcnt(0)" ::: "memory");
        __builtin_amdgcn_s_barrier();

#pragma unroll 1
        for (int s = 0; s < CHUNK; ++s) {
            const int rb = s & 1;              // read buffer (64 is even)
            // THIS lane's 32 h rows: replica q, rows [rq, rq+32)
            const v4f* hq = (const v4f*)&hbuf[rb][q][rq];

            v2f az = {0.f, 0.f}, ar = {0.f, 0.f}, an = {0.f, 0.f};

#define QROW(m, pa, pb) { const v4f h4 = hq[m]; \
    const v2f ha = __builtin_shufflevector(h4, h4, 0, 1); \
    const v2f hb = __builtin_shufflevector(h4, h4, 2, 3); \
    az = __builtin_elementwise_fma(ha, wz##pa, az); \
    az = __builtin_elementwise_fma(hb, wz##pb, az); \
    ar = __builtin_elementwise_fma(ha, wr##pa, ar); \
    ar = __builtin_elementwise_fma(hb, wr##pb, ar); \
    an = __builtin_elementwise_fma(ha, wn##pa, an); \
    an = __builtin_elementwise_fma(hb, wn##pb, an); }
            QROW(0, 0, 1)  QROW(1, 2, 3)   QROW(2, 4, 5)   QROW(3, 6, 7)
            QROW(4, 8, 9)  QROW(5, 10, 11) QROW(6, 12, 13) QROW(7, 14, 15)
#undef QROW

            // input projection: this lane's 2 x-features
            const v2f xv = *(const v2f*)&xsh[cb][(s << 3) + (q << 1)];
            az = __builtin_elementwise_fma(xv, kz, az);
            ar = __builtin_elementwise_fma(xv, kr, ar);
            v2f gx = {0.f, 0.f};
            gx = __builtin_elementwise_fma(xv, kn, gx);

            float pz  = az.x + az.y;
            float pr  = ar.x + ar.y;
            float pn  = an.x + an.y;
            float pxn = gx.x + gx.y;
            // quad reduction over q (rows 0..127 + all 8 features)
            pz  += dpp_xor1(pz);  pz  += dpp_xor2(pz);
            pr  += dpp_xor1(pr);  pr  += dpp_xor2(pr);
            pn  += dpp_xor1(pn);  pn  += dpp_xor2(pn);
            pxn += dpp_xor1(pxn); pxn += dpp_xor2(pxn);

            const float zarg = pz + bz;
            const float rarg = pr + brc;
            const float hn   = pn + brn;         // recurrent n (gated by r)
            const float xh   = pxn + bin;        // input n
            // sigmoid via native rcp/exp2 (1-ulp; no IEEE-div slow path)
            const float z  = rcpf_(1.0f + exp2f_(-LOG2E * zarg));
            const float rg = rcpf_(1.0f + exp2f_(-LOG2E * rarg));
            const float a2 = fmaf(rg, hn, xh);
            // tanh(a) = 1 - 2/(1 + exp(2a))
            const float hh = fmaf(-2.0f, rcpf_(1.0f + exp2f_(2.0f * LOG2E * a2)), 1.0f);
            const float hnew = fmaf(z, hprev - hh, hh);  // z*h + (1-z)*hh
            hprev = hnew;

            hbuf[rb ^ 1][q][col] = hnew;         // every lane: own replica
            if (q == 1) hist[s][col] = __float2bfloat16(hnew);  // LDS, 2B
            // one LDS-only wait + ONE barrier per step
            asm volatile("s_waitcnt lgkmcnt(0)" ::: "memory");
            __builtin_amdgcn_s_barrier();
        }

        // ---- chunk flush: hist[64][128] -> hsT, coalesced 16B stores ----
        {
            const int fc   = tid >> 2;          // col
            const int part = tid & 3;           // 16 steps each
            const int sb   = part << 4;
            unsigned int d[8];
#pragma unroll
            for (int j = 0; j < 8; ++j) {
                const unsigned int lo =
                    __builtin_bit_cast(unsigned short, hist[sb + 2 * j][fc]);
                const unsigned int hi =
                    __builtin_bit_cast(unsigned short, hist[sb + 2 * j + 1][fc]);
                d[j] = lo | (hi << 16);
            }
            v4u* dst = (v4u*)(hsT + (size_t)fc * T_STEPS + (c << 6) + sb);
            v4u d0; d0.x = d[0]; d0.y = d[1]; d0.z = d[2]; d0.w = d[3];
            v4u d1; d1.x = d[4]; d1.y = d[5]; d1.z = d[6]; d1.w = d[7];
            dst[0] = d0;                         // fire-and-forget
            dst[1] = d1;
        }
    }
}

// ---------------------------------------------------------------------------
// Dense tail: y[t][:] = hs[t][:] @ dk + db. Thread per t, W staged in LDS,
// float4 broadcast reads, coalesced bf16 reads from transposed hsT.
// ---------------------------------------------------------------------------
__global__ __launch_bounds__(256) void dense_out(
    const __hip_bfloat16* __restrict__ hsT,  // [128][T]
    const float* __restrict__ dk,            // [128][96]
    const float* __restrict__ db,            // [96]
    float* __restrict__ out)                 // [T][96]
{
    __shared__ float wl[128 * 96];
    for (int k = threadIdx.x; k < 128 * 96; k += 256) wl[k] = dk[k];
    __syncthreads();

    const int t = blockIdx.x * 256 + threadIdx.x;
    v4f acc[24];
#pragma unroll
    for (int o = 0; o < 24; ++o) acc[o] = ((const v4f*)db)[o];

#pragma unroll 4
    for (int i = 0; i < 128; ++i) {
        const float h = __bfloat162float(hsT[(size_t)i * T_STEPS + t]);
        const v4f* wp = (const v4f*)&wl[i * 96];
#pragma unroll
        for (int o = 0; o < 24; ++o) {
            const v4f wv = wp[o];
            acc[o].x = fmaf(h, wv.x, acc[o].x);
            acc[o].y = fmaf(h, wv.y, acc[o].y);
            acc[o].z = fmaf(h, wv.z, acc[o].z);
            acc[o].w = fmaf(h, wv.w, acc[o].w);
        }
    }
    v4f* op = (v4f*)(out + (size_t)t * 96);
#pragma unroll
    for (int o = 0; o < 24; ++o) op[o] = acc[o];
}

// ---------------------------------------------------------------------------
extern "C" void kernel_launch(void* const* d_in, const int* in_sizes, int n_in,
                              void* d_out, int out_size, void* d_ws, size_t ws_size,
                              hipStream_t stream) {
    const float* even_x = (const float*)d_in[0];
    const float* gk     = (const float*)d_in[1];
    const float* gr     = (const float*)d_in[2];
    const float* gb     = (const float*)d_in[3];
    const float* dk     = (const float*)d_in[4];
    const float* db     = (const float*)d_in[5];
    float* out          = (float*)d_out;

    // hsT needs 128*T*2 = 64 MiB. Guard against an undersized workspace:
    // fall back to d_out (valid 96 MiB) — output then fails absmax (tripwire)
    // instead of faulting the GPU with OOB writes.
    const size_t need = (size_t)128 * T_STEPS * sizeof(__hip_bfloat16);
    __hip_bfloat16* hsT = (ws_size >= need) ? (__hip_bfloat16*)d_ws
                                            : (__hip_bfloat16*)d_out;

    gru_scan<<<1, 512, 0, stream>>>(even_x, gk, gr, gb, hsT);
    dense_out<<<T_STEPS / 256, 256, 0, stream>>>(hsT, dk, db, out);
}